// Round 2
// baseline (526.690 us; speedup 1.0000x reference)
//
#include <hip/hip_runtime.h>
#include <stdint.h>

// Lorenz SDE, ShARK scheme. Streaming: read x[B,3], dW[B,5,3], dH[B,5,3] fp32,
// write yT[B,3]. Logical 576 MB -> HBM roofline ~90 us (less with L3 retention).
//
// R3: no-LDS register-direct streaming. R0/R1/R2 (LDS-staged, 3 different
// staging schemes) all pinned at 168 us / 1.9 TB/s / VALUBusy 15% -- the
// common structure was the cap: 33 KB LDS -> 16 waves/CU max, and
// batch-load->vmcnt(0)-drain convoys with effectively ~1 outstanding
// wave-load each (R2's global_load_lds null showed per-wave DMA
// serialization). The 6.3 TB/s copy ubench saturates with 32 waves/CU and
// ~1-2 outstanding loads/wave -- occupancy x continuity is the lever.
// Here: zero LDS, <=64 VGPR (launch_bounds(256,8)) -> 32 waves/CU,
// 2048 persistent blocks (8 blk/CU, all resident), grid-stride. Each lane
// loads its own point's 15+15+3 floats directly (4 overlapping 16B loads
// per noise array; per-lane stride 60 B still touches each 128B line once
// per wave, same HBM traffic). Bases are only 4B-aligned -> aligned(4)
// types; gfx950 unaligned-access mode handles dwordx4 at dword alignment.

#define BLOCK 256
#define MAXBLOCKS 2048

struct __attribute__((aligned(4))) F4 { float x, y, z, w; };
struct __attribute__((aligned(4))) F2 { float x, y; };
struct __attribute__((aligned(4))) F3 { float x, y, z; };

__global__ __launch_bounds__(BLOCK, 8) void lorenz_shark(
    const float* __restrict__ x,
    const float* __restrict__ dW,
    const float* __restrict__ dH,
    float* __restrict__ out,
    int batch)
{
    const int nthreads = gridDim.x * BLOCK;

    const float cW    = 0.2f;                  // NOISE * sqrt(dt)
    const float cH    = 0.05773502691896258f;  // NOISE * sqrt(dt/12)
    const float dt    = 0.01f;
    const float c56   = 5.0f / 6.0f;
    const float c56dt = c56 * dt;
    const float SIGMA = 10.0f;
    const float RHO   = 28.0f;
    const float BETA  = 8.0f / 3.0f;

#define STEP(WA,WB,WC,HA,HB,HC) do {                                  \
        const float wa=(WA)*cW, wb=(WB)*cW, wc=(WC)*cW;               \
        const float ha=(HA)*cH, hb=(HB)*cH, hc=(HC)*cH;               \
        const float z1a=a+ha, z1b=b+hb, z1c=c+hc;                     \
        const float f1a=SIGMA*(z1b-z1a);                              \
        const float f1b=z1a*(RHO-z1c)-z1b;                            \
        const float f1c=z1a*z1b-BETA*z1c;                             \
        const float z2a=a+c56dt*f1a+c56*wa+ha;                        \
        const float z2b=b+c56dt*f1b+c56*wb+hb;                        \
        const float z2c=c+c56dt*f1c+c56*wc+hc;                        \
        const float f2a=SIGMA*(z2b-z2a);                              \
        const float f2b=z2a*(RHO-z2c)-z2b;                            \
        const float f2c=z2a*z2b-BETA*z2c;                             \
        a=a+dt*(0.4f*f1a+0.6f*f2a)+wa;                                \
        b=b+dt*(0.4f*f1b+0.6f*f2b)+wb;                                \
        c=c+dt*(0.4f*f1c+0.6f*f2c)+wc;                                \
    } while (0)

    for (int pt = blockIdx.x * BLOCK + threadIdx.x; pt < batch; pt += nthreads) {
        const float* wp = dW + (size_t)pt * 15;
        const float* hp = dH + (size_t)pt * 15;
        const float* xp = x  + (size_t)pt * 3;

        // 15 floats each via 4 overlapping 16B loads (last covers [11,15)).
        const F4 w0 = *(const F4*)(wp);
        const F4 w1 = *(const F4*)(wp + 4);
        const F4 w2 = *(const F4*)(wp + 8);
        const F4 w3 = *(const F4*)(wp + 11);
        const F4 h0 = *(const F4*)(hp);
        const F4 h1 = *(const F4*)(hp + 4);
        const F4 h2 = *(const F4*)(hp + 8);
        const F4 h3 = *(const F4*)(hp + 11);
        const F2 xab = *(const F2*)(xp);
        float a = xab.x, b = xab.y, c = xp[2];

        // step n uses floats [3n, 3n+2] of w/h:
        STEP(w0.x, w0.y, w0.z,  h0.x, h0.y, h0.z);   // 0,1,2
        STEP(w0.w, w1.x, w1.y,  h0.w, h1.x, h1.y);   // 3,4,5
        STEP(w1.z, w1.w, w2.x,  h1.z, h1.w, h2.x);   // 6,7,8
        STEP(w2.y, w2.z, w2.w,  h2.y, h2.z, h2.w);   // 9,10,11
        STEP(w3.y, w3.z, w3.w,  h3.y, h3.z, h3.w);   // 12,13,14 (w3=[11,15))

        F3 r; r.x = a; r.y = b; r.z = c;
        *(F3*)(out + (size_t)pt * 3) = r;
    }
#undef STEP
}

extern "C" void kernel_launch(void* const* d_in, const int* in_sizes, int n_in,
                              void* d_out, int out_size, void* d_ws, size_t ws_size,
                              hipStream_t stream) {
    const float* x  = (const float*)d_in[0];
    const float* dW = (const float*)d_in[1];
    const float* dH = (const float*)d_in[2];
    float* out = (float*)d_out;

    const int batch = in_sizes[0] / 3;            // 4194304
    int nblocks = (batch + BLOCK - 1) / BLOCK;
    if (nblocks > MAXBLOCKS) nblocks = MAXBLOCKS; // 2048: 8 blk/CU persistent

    hipLaunchKernelGGL(lorenz_shark, dim3(nblocks), dim3(BLOCK), 0, stream,
                       x, dW, dH, out, batch);
}

// Round 3
// 523.996 us; speedup vs baseline: 1.0051x; 1.0051x over previous
//
#include <hip/hip_runtime.h>
#include <stdint.h>

// Lorenz SDE, ShARK scheme. Streaming: read x[B,3], dW[B,5,3], dH[B,5,3] fp32,
// write yT[B,3]. Logical 604 MB -> HBM roofline ~90 us.
//
// R4: persistent double-buffered DMA pipeline (T3+T4 for streaming).
// R0-R3 (4 different structures) all pinned at ~170us / 2.0 TB/s HBM:
// the invariant was convoy issue -- every variant drained its loads to zero
// before computing (vmcnt(0), or VGPR-recycling serialization at 32-52 regs),
// so in-flight bytes/CU averaged far below the ~20 KB Little's-law need.
// Here: 512 persistent blocks (2/CU, LDS-capped), each wave loops 32 tiles;
// tile t+1's 9 global_load_lds DMAs (9KB, zero data VGPRs) stay posted while
// tile t computes. Counted s_waitcnt vmcnt(9) -- NEVER 0 in the main loop.
// 8 waves/CU x 9-18KB posted = ~72-144 KB/CU in flight, continuously.
// Wave-strided tiles: at step t, the 2048 waves cover a contiguous ~32MB
// window sweeping memory (DRAM-row friendly).

#define NSTEPS 5
#define BLOCK 256
#define WPB 4          // waves per block
#define TILE 64        // points per wave-tile
#define GRID 512       // 2 blocks/CU persistent

__device__ __forceinline__ void gll16(const float4* g, float* l) {
    __builtin_amdgcn_global_load_lds(
        (const __attribute__((address_space(1))) void*)g,
        (__attribute__((address_space(3))) void*)l,
        16, 0, 0);
}

__global__ __launch_bounds__(BLOCK) void lorenz_shark(
    const float* __restrict__ x,
    const float* __restrict__ dW,
    const float* __restrict__ dH,
    float* __restrict__ out,
    int batch)
{
    // double-buffered per-wave slices: 2*(3840+3840+768)B * 4 waves = 67584 B
    __shared__ float s_w[2][WPB][TILE * 15];
    __shared__ float s_h[2][WPB][TILE * 15];
    __shared__ float s_x[2][WPB][TILE * 3];

    const int lane   = threadIdx.x & 63;
    const int wv     = threadIdx.x >> 6;
    const int waveId = blockIdx.x * WPB + wv;      // 0..2047
    const int nWaves = GRID * WPB;                 // 2048
    const int nTiles = batch / TILE;               // 65536
    const int NTbase = nTiles / nWaves;            // 32 for this shape
    const int rem    = nTiles - NTbase * nWaves;   // 0 for this shape
    const int NT     = NTbase + (waveId < rem ? 1 : 0);

    // stage tile -> LDS buffer buf: 9 global_load_lds dwordx4, wave-uniform
    // LDS base + lane*16 (hardware DMA layout == our linear layout).
    auto stage = [&](int buf, long long tile) {
        const float4* gw = (const float4*)(dW + tile * (TILE * 15));
        const float4* gh = (const float4*)(dH + tile * (TILE * 15));
        const float4* gx = (const float4*)(x  + tile * (TILE * 3));
        float* lw = s_w[buf][wv];
        float* lh = s_h[buf][wv];
        float* lx = s_x[buf][wv];
#pragma unroll
        for (int k = 0; k < 3; ++k) {
            gll16(gw + lane + k * 64, lw + k * 256);
            gll16(gh + lane + k * 64, lh + k * 256);
        }
        if (lane < 48) {
            gll16(gw + lane + 192, lw + 768);
            gll16(gh + lane + 192, lh + 768);
            gll16(gx + lane,       lx);
        }
    };

    const float cW    = 0.2f;                  // NOISE * sqrt(dt)
    const float cH    = 0.05773502691896258f;  // NOISE * sqrt(dt/12)
    const float dt    = 0.01f;
    const float c56   = 5.0f / 6.0f;
    const float c56dt = c56 * dt;
    const float SIGMA = 10.0f;
    const float RHO   = 28.0f;
    const float BETA  = 8.0f / 3.0f;

    if (NT <= 0) return;
    stage(0, (long long)waveId);                   // prologue: post tile 0

    for (int t = 0; t < NT; ++t) {
        // post next tile's 9 loads BEFORE waiting on current tile's.
        if (t + 1 < NT) {
            stage((t + 1) & 1, (long long)waveId + (long long)(t + 1) * nWaves);
            // outstanding: 9(new) + 9(cur tile) + 1(prev store).
            // vmcnt(9): drain cur tile + store, keep the 9 prefetch posted.
            asm volatile("s_waitcnt vmcnt(9)" ::: "memory");
        } else {
            asm volatile("s_waitcnt vmcnt(0)" ::: "memory");
        }
        __builtin_amdgcn_sched_barrier(0);

        const int buf = t & 1;
        const float* sw = s_w[buf][wv];
        const float* sh = s_h[buf][wv];
        float*       sx = s_x[buf][wv];

        float a = sx[3 * lane + 0];
        float b = sx[3 * lane + 1];
        float c = sx[3 * lane + 2];

#pragma unroll
        for (int n = 0; n < NSTEPS; ++n) {
            const int w0 = 15 * lane + 3 * n;      // stride 15: 2 lanes/bank, free
            const float wa = sw[w0 + 0] * cW;
            const float wb = sw[w0 + 1] * cW;
            const float wc = sw[w0 + 2] * cW;
            const float ha = sh[w0 + 0] * cH;
            const float hb = sh[w0 + 1] * cH;
            const float hc = sh[w0 + 2] * cH;

            const float z1a = a + ha, z1b = b + hb, z1c = c + hc;
            const float f1a = SIGMA * (z1b - z1a);
            const float f1b = z1a * (RHO - z1c) - z1b;
            const float f1c = z1a * z1b - BETA * z1c;

            const float z2a = a + c56dt * f1a + c56 * wa + ha;
            const float z2b = b + c56dt * f1b + c56 * wb + hb;
            const float z2c = c + c56dt * f1c + c56 * wc + hc;
            const float f2a = SIGMA * (z2b - z2a);
            const float f2b = z2a * (RHO - z2c) - z2b;
            const float f2c = z2a * z2b - BETA * z2c;

            a = a + dt * (0.4f * f1a + 0.6f * f2a) + wa;
            b = b + dt * (0.4f * f1b + 0.6f * f2b) + wb;
            c = c + dt * (0.4f * f1c + 0.6f * f2c) + wc;
        }

        // result -> LDS bounce -> coalesced float4 store (intra-wave order)
        sx[3 * lane + 0] = a;
        sx[3 * lane + 1] = b;
        sx[3 * lane + 2] = c;
        __builtin_amdgcn_wave_barrier();

        const long long tile = (long long)waveId + (long long)t * nWaves;
        float4* go = (float4*)(out + tile * (TILE * 3));
        const float4* lx4 = (const float4*)sx;
        if (lane < 48) go[lane] = lx4[lane];       // 1 vmem store (the +1 counted)
    }
}

extern "C" void kernel_launch(void* const* d_in, const int* in_sizes, int n_in,
                              void* d_out, int out_size, void* d_ws, size_t ws_size,
                              hipStream_t stream) {
    const float* x  = (const float*)d_in[0];
    const float* dW = (const float*)d_in[1];
    const float* dH = (const float*)d_in[2];
    float* out = (float*)d_out;

    const int batch = in_sizes[0] / 3;            // 4194304

    hipLaunchKernelGGL(lorenz_shark, dim3(GRID), dim3(BLOCK), 0, stream,
                       x, dW, dH, out, batch);
}